// Round 1
// baseline (2192.586 us; speedup 1.0000x reference)
//
#include <hip/hip_runtime.h>

// Self-attention, fp32, MODEL_DIM=1024, BATCH=4, SEQ=2048.
// Pipeline: QKV projection GEMMs (NT) -> per batch: scores GEMM (NT, scaled),
// row softmax, PV GEMM (NN). All fp32 vector math (no fp32 MFMA on CDNA4).

constexpr int MDIM = 1024;
constexpr int NBATCH = 4;
constexpr int SEQL = 2048;

#define BM 128
#define BN 128
#define BK 16
#define LPAD 4  // LDS row padding (floats)

// C[M,N] = alpha * A[M,K] * op(B)
// TRANS_B=true : B is [N,K] row-major (C = A * B^T)  -- projections, QK^T
// TRANS_B=false: B is [K,N] row-major (C = A * B)    -- P*V
template <bool TRANS_B>
__global__ __launch_bounds__(256) void gemm128(const float* __restrict__ A,
                                               const float* __restrict__ Bm,
                                               float* __restrict__ C, int M,
                                               int N, int K, float alpha) {
  __shared__ float As[BK][BM + LPAD];
  __shared__ float Bs[BK][BN + LPAD];

  const int tid = threadIdx.x;
  const int m0 = blockIdx.y * BM;
  const int n0 = blockIdx.x * BN;

  const int tm = (tid >> 4) & 15;  // 0..15
  const int tn = tid & 15;         // 0..15

  // Global-load indices: 128 rows x 16 k per tile; thread pair covers one
  // row's 64B (two float4 along k).
  const int lr = tid >> 1;         // 0..127 (row of A tile / row of B^T tile)
  const int lk = (tid & 1) * 8;    // 0 or 8

  float acc[8][8];
#pragma unroll
  for (int i = 0; i < 8; ++i)
#pragma unroll
    for (int j = 0; j < 8; ++j) acc[i][j] = 0.0f;

  for (int k0 = 0; k0 < K; k0 += BK) {
    // ---- global loads into registers ----
    const float4 a0 = *(const float4*)&A[(size_t)(m0 + lr) * K + k0 + lk];
    const float4 a1 = *(const float4*)&A[(size_t)(m0 + lr) * K + k0 + lk + 4];
    float4 b0, b1;
    if (TRANS_B) {
      b0 = *(const float4*)&Bm[(size_t)(n0 + lr) * K + k0 + lk];
      b1 = *(const float4*)&Bm[(size_t)(n0 + lr) * K + k0 + lk + 4];
    } else {
      const int krow = tid >> 4;        // 0..15
      const int nc = (tid & 15) * 4;    // 0..60
      b0 = *(const float4*)&Bm[(size_t)(k0 + krow) * N + n0 + nc];
      b1 = *(const float4*)&Bm[(size_t)(k0 + krow) * N + n0 + 64 + nc];
    }

    __syncthreads();  // previous tile fully consumed

    // ---- store to LDS (A transposed to [k][m]) ----
    As[lk + 0][lr] = a0.x;
    As[lk + 1][lr] = a0.y;
    As[lk + 2][lr] = a0.z;
    As[lk + 3][lr] = a0.w;
    As[lk + 4][lr] = a1.x;
    As[lk + 5][lr] = a1.y;
    As[lk + 6][lr] = a1.z;
    As[lk + 7][lr] = a1.w;
    if (TRANS_B) {
      Bs[lk + 0][lr] = b0.x;
      Bs[lk + 1][lr] = b0.y;
      Bs[lk + 2][lr] = b0.z;
      Bs[lk + 3][lr] = b0.w;
      Bs[lk + 4][lr] = b1.x;
      Bs[lk + 5][lr] = b1.y;
      Bs[lk + 6][lr] = b1.z;
      Bs[lk + 7][lr] = b1.w;
    } else {
      const int krow = tid >> 4;
      const int nc = (tid & 15) * 4;
      *(float4*)&Bs[krow][nc] = b0;
      *(float4*)&Bs[krow][64 + nc] = b1;
    }

    __syncthreads();

    // ---- 8x8 micro-tile FMA (split 4+4 at offsets 0/64: 2-way LDS alias) ----
#pragma unroll
    for (int kk = 0; kk < BK; ++kk) {
      const float4 av0 = *(const float4*)&As[kk][tm * 4];
      const float4 av1 = *(const float4*)&As[kk][64 + tm * 4];
      const float4 bv0 = *(const float4*)&Bs[kk][tn * 4];
      const float4 bv1 = *(const float4*)&Bs[kk][64 + tn * 4];
      const float ar[8] = {av0.x, av0.y, av0.z, av0.w,
                           av1.x, av1.y, av1.z, av1.w};
      const float br[8] = {bv0.x, bv0.y, bv0.z, bv0.w,
                           bv1.x, bv1.y, bv1.z, bv1.w};
#pragma unroll
      for (int i = 0; i < 8; ++i)
#pragma unroll
        for (int j = 0; j < 8; ++j) acc[i][j] = fmaf(ar[i], br[j], acc[i][j]);
    }
  }

  // ---- epilogue ----
#pragma unroll
  for (int i = 0; i < 8; ++i) {
    const int r = m0 + ((i < 4) ? (tm * 4 + i) : (64 + tm * 4 + (i - 4)));
    float4 o0, o1;
    o0.x = acc[i][0] * alpha;
    o0.y = acc[i][1] * alpha;
    o0.z = acc[i][2] * alpha;
    o0.w = acc[i][3] * alpha;
    o1.x = acc[i][4] * alpha;
    o1.y = acc[i][5] * alpha;
    o1.z = acc[i][6] * alpha;
    o1.w = acc[i][7] * alpha;
    *(float4*)&C[(size_t)r * N + n0 + tn * 4] = o0;
    *(float4*)&C[(size_t)r * N + n0 + 64 + tn * 4] = o1;
  }
}

// In-place row softmax, one 256-thread WG per row of 2048 floats.
__global__ __launch_bounds__(256) void softmax2048(float* __restrict__ S) {
  float* p = S + (size_t)blockIdx.x * 2048;
  const int tid = threadIdx.x;

  float4 v0 = *(float4*)&p[tid * 8];
  float4 v1 = *(float4*)&p[tid * 8 + 4];

  float m = fmaxf(fmaxf(fmaxf(v0.x, v0.y), fmaxf(v0.z, v0.w)),
                  fmaxf(fmaxf(v1.x, v1.y), fmaxf(v1.z, v1.w)));
#pragma unroll
  for (int off = 32; off > 0; off >>= 1) m = fmaxf(m, __shfl_xor(m, off));

  __shared__ float redm[4];
  __shared__ float reds[4];
  if ((tid & 63) == 0) redm[tid >> 6] = m;
  __syncthreads();
  m = fmaxf(fmaxf(redm[0], redm[1]), fmaxf(redm[2], redm[3]));

  v0.x = __expf(v0.x - m);
  v0.y = __expf(v0.y - m);
  v0.z = __expf(v0.z - m);
  v0.w = __expf(v0.w - m);
  v1.x = __expf(v1.x - m);
  v1.y = __expf(v1.y - m);
  v1.z = __expf(v1.z - m);
  v1.w = __expf(v1.w - m);

  float s = (v0.x + v0.y) + (v0.z + v0.w) + (v1.x + v1.y) + (v1.z + v1.w);
#pragma unroll
  for (int off = 32; off > 0; off >>= 1) s += __shfl_xor(s, off);
  if ((tid & 63) == 0) reds[tid >> 6] = s;
  __syncthreads();
  s = (reds[0] + reds[1]) + (reds[2] + reds[3]);

  const float inv = 1.0f / s;
  v0.x *= inv;
  v0.y *= inv;
  v0.z *= inv;
  v0.w *= inv;
  v1.x *= inv;
  v1.y *= inv;
  v1.z *= inv;
  v1.w *= inv;

  *(float4*)&p[tid * 8] = v0;
  *(float4*)&p[tid * 8 + 4] = v1;
}

extern "C" void kernel_launch(void* const* d_in, const int* in_sizes, int n_in,
                              void* d_out, int out_size, void* d_ws,
                              size_t ws_size, hipStream_t stream) {
  const float* x = (const float*)d_in[0];
  const float* Wq = (const float*)d_in[1];
  const float* Wk = (const float*)d_in[2];
  const float* Wv = (const float*)d_in[3];
  float* out = (float*)d_out;

  const int ROWS = NBATCH * SEQL;  // 8192
  float* Q = (float*)d_ws;
  float* K = Q + (size_t)ROWS * MDIM;
  float* V = K + (size_t)ROWS * MDIM;
  float* Sc = V + (size_t)ROWS * MDIM;  // one batch of scores: 2048x2048

  const dim3 blk(256);

  // QKV projections: [8192,1024] = x[8192,1024] * W[1024,1024]^T
  {
    const dim3 g(MDIM / BN, ROWS / BM);
    gemm128<true><<<g, blk, 0, stream>>>(x, Wq, Q, ROWS, MDIM, MDIM, 1.0f);
    gemm128<true><<<g, blk, 0, stream>>>(x, Wk, K, ROWS, MDIM, MDIM, 1.0f);
    gemm128<true><<<g, blk, 0, stream>>>(x, Wv, V, ROWS, MDIM, MDIM, 1.0f);
  }

  const float scale = 1.0f / 32.0f;  // 1/sqrt(1024)
  for (int b = 0; b < NBATCH; ++b) {
    const float* Qb = Q + (size_t)b * SEQL * MDIM;
    const float* Kb = K + (size_t)b * SEQL * MDIM;
    const float* Vb = V + (size_t)b * SEQL * MDIM;
    float* Ob = out + (size_t)b * SEQL * MDIM;

    // scores = scale * Qb * Kb^T  [2048,2048]
    {
      const dim3 g(SEQL / BN, SEQL / BM);
      gemm128<true><<<g, blk, 0, stream>>>(Qb, Kb, Sc, SEQL, SEQL, MDIM,
                                           scale);
    }
    // softmax rows in place
    softmax2048<<<SEQL, blk, 0, stream>>>(Sc);
    // out = P * Vb  [2048,1024]
    {
      const dim3 g(MDIM / BN, SEQL / BM);
      gemm128<false><<<g, blk, 0, stream>>>(Sc, Vb, Ob, SEQL, MDIM, SEQL,
                                            1.0f);
    }
  }
}

// Round 2
// 208.602 us; speedup vs baseline: 10.5108x; 10.5108x over previous
//
#include <hip/hip_runtime.h>
#include <hip/hip_bf16.h>

// Self-attention, MODEL_DIM=1024, BATCH=4, SEQ=2048.
// bf16 MFMA pipeline: cast -> Q,K,V^T projections (NT GEMM) ->
// scores=Q.K^T (z-batched, alpha=1/32, bf16) -> in-place softmax ->
// out = P.(V^T)^T (NT GEMM, fp32 out).

typedef short bf16x8_t __attribute__((ext_vector_type(8)));
typedef float f32x4_t __attribute__((ext_vector_type(4)));
typedef unsigned short u16x8_t __attribute__((ext_vector_type(8)));

static __device__ __forceinline__ unsigned short f2bf(float f) {
  __hip_bfloat16 h = __float2bfloat16(f);
  return *reinterpret_cast<unsigned short*>(&h);
}
static __device__ __forceinline__ float bf2f(unsigned short u) {
  return __uint_as_float(((unsigned int)u) << 16);
}

#define GLOAD_LDS16(gp, lp)                                            \
  __builtin_amdgcn_global_load_lds(                                    \
      (const __attribute__((address_space(1))) void*)(gp),             \
      (__attribute__((address_space(3))) void*)(lp), 16, 0, 0)

// ---------------------------------------------------------------------------
// cast fp32 -> bf16, 8 elements/thread
__global__ __launch_bounds__(256) void cast_f32_bf16(
    const float* __restrict__ in, unsigned short* __restrict__ out, int n8) {
  int i = blockIdx.x * 256 + threadIdx.x;
  if (i >= n8) return;
  float4 a = ((const float4*)in)[i * 2];
  float4 b = ((const float4*)in)[i * 2 + 1];
  u16x8_t o;
  o[0] = f2bf(a.x);
  o[1] = f2bf(a.y);
  o[2] = f2bf(a.z);
  o[3] = f2bf(a.w);
  o[4] = f2bf(b.x);
  o[5] = f2bf(b.y);
  o[6] = f2bf(b.z);
  o[7] = f2bf(b.w);
  ((u16x8_t*)out)[i] = o;
}

// ---------------------------------------------------------------------------
// NT bf16 GEMM: C[M,N] = alpha * A[M,K] * B[N,K]^T   (all row-major)
// 128x128 tile, BK=64, 256 threads = 4 waves (2x2), 64x64 per wave,
// 4x4 fragments of v_mfma_f32_16x16x32_bf16.
// LDS tiles [128][64] bf16, chunk-swizzled: phys_chunk = r*8 + (c8 ^ (r&7)).
// Staged via global_load_lds (linear LDS dest, pre-swizzled global source).
template <bool OUT_BF16>
__global__ __launch_bounds__(256) void gemm_nt(
    const unsigned short* __restrict__ A, const unsigned short* __restrict__ B,
    void* __restrict__ Cv, int M, int N, int K, int lda, int ldb, int ldc,
    long long sA, long long sB, long long sC, float alpha) {
  __shared__ unsigned short As[128 * 64];
  __shared__ unsigned short Bs[128 * 64];

  const int tid = threadIdx.x;
  const int lane = tid & 63;
  const int w = tid >> 6;
  const int wm = w >> 1, wn = w & 1;
  const int z = blockIdx.z;
  const int m0 = blockIdx.y * 128;
  const int n0 = blockIdx.x * 128;

  A += (long long)z * sA;
  B += (long long)z * sB;

  // staging: inst i covers phys chunks [w*256 + i*64, +64); lane -> one chunk.
  // phys = r*8 + (c8 ^ (r&7))  =>  fetch logical c8 = (phys&7) ^ (r&7).
  int srow[4], scol[4];
#pragma unroll
  for (int i = 0; i < 4; ++i) {
    int p = w * 256 + i * 64 + lane;
    int r = p >> 3;
    int c8 = (p & 7) ^ (r & 7);
    srow[i] = r;
    scol[i] = c8 * 8;  // element offset along k
  }

  // ds_read element offsets (K-iteration invariant)
  const int q = lane >> 4, rl = lane & 15;
  int aoff[4][2], boff[4][2];
#pragma unroll
  for (int t = 0; t < 4; ++t) {
#pragma unroll
    for (int ks = 0; ks < 2; ++ks) {
      int ra = wm * 64 + t * 16 + rl;
      int ca = ks * 4 + q;
      aoff[t][ks] = ra * 64 + ((ca ^ (ra & 7)) * 8);
      int rb = wn * 64 + t * 16 + rl;
      boff[t][ks] = rb * 64 + ((ca ^ (rb & 7)) * 8);
    }
  }

  f32x4_t acc[4][4];
#pragma unroll
  for (int i = 0; i < 4; ++i)
#pragma unroll
    for (int j = 0; j < 4; ++j) acc[i][j] = (f32x4_t){0.f, 0.f, 0.f, 0.f};

  for (int k0 = 0; k0 < K; k0 += 64) {
    __syncthreads();  // previous tile fully consumed
#pragma unroll
    for (int i = 0; i < 4; ++i) {
      GLOAD_LDS16(&A[(long long)(m0 + srow[i]) * lda + k0 + scol[i]],
                  &As[(w * 4 + i) * 512]);
    }
#pragma unroll
    for (int i = 0; i < 4; ++i) {
      GLOAD_LDS16(&B[(long long)(n0 + srow[i]) * ldb + k0 + scol[i]],
                  &Bs[(w * 4 + i) * 512]);
    }
    __syncthreads();  // drains vmcnt(0): tiles resident

#pragma unroll
    for (int ks = 0; ks < 2; ++ks) {
      bf16x8_t af[4], bg[4];
#pragma unroll
      for (int t = 0; t < 4; ++t) af[t] = *(const bf16x8_t*)&As[aoff[t][ks]];
#pragma unroll
      for (int t = 0; t < 4; ++t) bg[t] = *(const bf16x8_t*)&Bs[boff[t][ks]];
#pragma unroll
      for (int i = 0; i < 4; ++i)
#pragma unroll
        for (int j = 0; j < 4; ++j)
          acc[i][j] = __builtin_amdgcn_mfma_f32_16x16x32_bf16(af[i], bg[j],
                                                              acc[i][j], 0, 0, 0);
    }
  }

  // epilogue: C[row=(l>>4)*4+j][col=l&15] per fragment
  if (OUT_BF16) {
    unsigned short* C = (unsigned short*)Cv + (long long)z * sC;
#pragma unroll
    for (int t = 0; t < 4; ++t)
#pragma unroll
      for (int u = 0; u < 4; ++u)
#pragma unroll
        for (int j = 0; j < 4; ++j) {
          int row = m0 + wm * 64 + t * 16 + q * 4 + j;
          int col = n0 + wn * 64 + u * 16 + rl;
          C[(long long)row * ldc + col] = f2bf(acc[t][u][j] * alpha);
        }
  } else {
    float* C = (float*)Cv + (long long)z * sC;
#pragma unroll
    for (int t = 0; t < 4; ++t)
#pragma unroll
      for (int u = 0; u < 4; ++u)
#pragma unroll
        for (int j = 0; j < 4; ++j) {
          int row = m0 + wm * 64 + t * 16 + q * 4 + j;
          int col = n0 + wn * 64 + u * 16 + rl;
          C[(long long)row * ldc + col] = acc[t][u][j] * alpha;
        }
  }
}

// ---------------------------------------------------------------------------
// in-place row softmax on bf16 rows of 2048; fp32 internal math.
__global__ __launch_bounds__(256) void softmax_bf16(
    unsigned short* __restrict__ S) {
  unsigned short* p = S + (long long)blockIdx.x * 2048;
  const int tid = threadIdx.x;

  u16x8_t v = ((u16x8_t*)p)[tid];
  float f[8];
#pragma unroll
  for (int j = 0; j < 8; ++j) f[j] = bf2f(v[j]);

  float m = f[0];
#pragma unroll
  for (int j = 1; j < 8; ++j) m = fmaxf(m, f[j]);
#pragma unroll
  for (int off = 32; off > 0; off >>= 1) m = fmaxf(m, __shfl_xor(m, off));

  __shared__ float redm[4];
  __shared__ float reds[4];
  if ((tid & 63) == 0) redm[tid >> 6] = m;
  __syncthreads();
  m = fmaxf(fmaxf(redm[0], redm[1]), fmaxf(redm[2], redm[3]));

  float s = 0.f;
#pragma unroll
  for (int j = 0; j < 8; ++j) {
    f[j] = __expf(f[j] - m);
    s += f[j];
  }
#pragma unroll
  for (int off = 32; off > 0; off >>= 1) s += __shfl_xor(s, off);
  if ((tid & 63) == 0) reds[tid >> 6] = s;
  __syncthreads();
  s = (reds[0] + reds[1]) + (reds[2] + reds[3]);

  const float inv = 1.0f / s;
#pragma unroll
  for (int j = 0; j < 8; ++j) v[j] = f2bf(f[j] * inv);
  ((u16x8_t*)p)[tid] = v;
}

// ---------------------------------------------------------------------------
extern "C" void kernel_launch(void* const* d_in, const int* in_sizes, int n_in,
                              void* d_out, int out_size, void* d_ws,
                              size_t ws_size, hipStream_t stream) {
  const float* x = (const float*)d_in[0];
  const float* Wq = (const float*)d_in[1];
  const float* Wk = (const float*)d_in[2];
  const float* Wv = (const float*)d_in[3];
  float* out = (float*)d_out;

  // workspace layout (ushort elements)
  unsigned short* xb = (unsigned short*)d_ws;                  // 8192x1024
  unsigned short* Wqb = xb + 8388608;                          // 1024x1024
  unsigned short* Wkb = Wqb + 1048576;
  unsigned short* Wvb = Wkb + 1048576;
  unsigned short* Qb = Wvb + 1048576;                          // 8192x1024
  unsigned short* Kb = Qb + 8388608;                           // 8192x1024
  unsigned short* VTb = Kb + 8388608;                          // 1024x8192
  unsigned short* Scb = VTb + 8388608;                         // 4x2048x2048

  const dim3 blk(256);

  cast_f32_bf16<<<4096, blk, 0, stream>>>(x, xb, 1048576);
  cast_f32_bf16<<<512, blk, 0, stream>>>(Wq, Wqb, 131072);
  cast_f32_bf16<<<512, blk, 0, stream>>>(Wk, Wkb, 131072);
  cast_f32_bf16<<<512, blk, 0, stream>>>(Wv, Wvb, 131072);

  // Q = x.Wq^T [8192,1024]; K = x.Wk^T; V^T = Wv.x^T [1024,8192]
  gemm_nt<true><<<dim3(8, 64, 1), blk, 0, stream>>>(
      xb, Wqb, Qb, 8192, 1024, 1024, 1024, 1024, 1024, 0, 0, 0, 1.0f);
  gemm_nt<true><<<dim3(8, 64, 1), blk, 0, stream>>>(
      xb, Wkb, Kb, 8192, 1024, 1024, 1024, 1024, 1024, 0, 0, 0, 1.0f);
  gemm_nt<true><<<dim3(64, 8, 1), blk, 0, stream>>>(
      Wvb, xb, VTb, 1024, 8192, 1024, 1024, 1024, 8192, 0, 0, 0, 1.0f);

  // scores = (1/32) Qb.Kb^T  per batch -> bf16, in-place softmax
  gemm_nt<true><<<dim3(16, 16, 4), blk, 0, stream>>>(
      Qb, Kb, Scb, 2048, 2048, 1024, 1024, 1024, 2048, (long long)2048 * 1024,
      (long long)2048 * 1024, (long long)2048 * 2048, 0.03125f);

  softmax_bf16<<<8192, blk, 0, stream>>>(Scb);

  // out = P.(V^T)^T : A=P [2048,2048] lda=2048, B=VT rows ldb=8192 (z-offset
  // 2048 cols), C fp32 [2048,1024]
  gemm_nt<false><<<dim3(8, 16, 4), blk, 0, stream>>>(
      Scb, VTb, out, 2048, 1024, 2048, 2048, 8192, 1024,
      (long long)2048 * 2048, 2048, (long long)2048 * 1024, 1.0f);
}

// Round 3
// 197.966 us; speedup vs baseline: 11.0756x; 1.0537x over previous
//
#include <hip/hip_runtime.h>
#include <hip/hip_bf16.h>

// Self-attention, MODEL_DIM=1024, BATCH=4, SEQ=2048.
// bf16 MFMA pipeline: cast -> Q,K,V^T projections (NT GEMM) ->
// scores=Q.K^T (z-batched, alpha=1/32, bf16) -> in-place softmax ->
// out = P.(V^T)^T (NT GEMM, fp32 out).
// R3: + bijective XCD-aware block swizzle (T1) on all GEMM dispatches.

typedef short bf16x8_t __attribute__((ext_vector_type(8)));
typedef float f32x4_t __attribute__((ext_vector_type(4)));
typedef unsigned short u16x8_t __attribute__((ext_vector_type(8)));

static __device__ __forceinline__ unsigned short f2bf(float f) {
  __hip_bfloat16 h = __float2bfloat16(f);
  return *reinterpret_cast<unsigned short*>(&h);
}
static __device__ __forceinline__ float bf2f(unsigned short u) {
  return __uint_as_float(((unsigned int)u) << 16);
}

#define GLOAD_LDS16(gp, lp)                                            \
  __builtin_amdgcn_global_load_lds(                                    \
      (const __attribute__((address_space(1))) void*)(gp),             \
      (__attribute__((address_space(3))) void*)(lp), 16, 0, 0)

// ---------------------------------------------------------------------------
// cast fp32 -> bf16, 8 elements/thread
__global__ __launch_bounds__(256) void cast_f32_bf16(
    const float* __restrict__ in, unsigned short* __restrict__ out, int n8) {
  int i = blockIdx.x * 256 + threadIdx.x;
  if (i >= n8) return;
  float4 a = ((const float4*)in)[i * 2];
  float4 b = ((const float4*)in)[i * 2 + 1];
  u16x8_t o;
  o[0] = f2bf(a.x);
  o[1] = f2bf(a.y);
  o[2] = f2bf(a.z);
  o[3] = f2bf(a.w);
  o[4] = f2bf(b.x);
  o[5] = f2bf(b.y);
  o[6] = f2bf(b.z);
  o[7] = f2bf(b.w);
  ((u16x8_t*)out)[i] = o;
}

// ---------------------------------------------------------------------------
// NT bf16 GEMM: C[M,N] = alpha * A[M,K] * B[N,K]^T   (all row-major)
// 128x128 tile, BK=64, 256 threads = 4 waves (2x2), 64x64 per wave,
// 4x4 fragments of v_mfma_f32_16x16x32_bf16.
// LDS tiles [128][64] bf16, chunk-swizzled: phys_chunk = r*8 + (c8 ^ (r&7)).
// Staged via global_load_lds (linear LDS dest, pre-swizzled global source).
// Block ids XCD-swizzled: XCD k owns a contiguous chunk of the linear grid
// so per-XCD L2 holds the operand panels (fixes 7.7x HBM overfetch).
template <bool OUT_BF16>
__global__ __launch_bounds__(256) void gemm_nt(
    const unsigned short* __restrict__ A, const unsigned short* __restrict__ B,
    void* __restrict__ Cv, int M, int N, int K, int lda, int ldb, int ldc,
    long long sA, long long sB, long long sC, float alpha) {
  __shared__ unsigned short As[128 * 64];
  __shared__ unsigned short Bs[128 * 64];

  // ---- T1: bijective XCD swizzle (all grids here have nwg % 8 == 0) ----
  const int gx = gridDim.x, gy = gridDim.y;
  const int nwg = gx * gy * gridDim.z;
  const int orig = (blockIdx.z * gy + blockIdx.y) * gx + blockIdx.x;
  const int swz = (orig & 7) * (nwg >> 3) + (orig >> 3);
  const int bx = swz % gx;
  const int tmp = swz / gx;
  const int by = tmp % gy;
  const int z = tmp / gy;

  const int tid = threadIdx.x;
  const int lane = tid & 63;
  const int w = tid >> 6;
  const int wm = w >> 1, wn = w & 1;
  const int m0 = by * 128;
  const int n0 = bx * 128;

  A += (long long)z * sA;
  B += (long long)z * sB;

  // staging: inst i covers phys chunks [w*256 + i*64, +64); lane -> one chunk.
  // phys = r*8 + (c8 ^ (r&7))  =>  fetch logical c8 = (phys&7) ^ (r&7).
  int srow[4], scol[4];
#pragma unroll
  for (int i = 0; i < 4; ++i) {
    int p = w * 256 + i * 64 + lane;
    int r = p >> 3;
    int c8 = (p & 7) ^ (r & 7);
    srow[i] = r;
    scol[i] = c8 * 8;  // element offset along k
  }

  // ds_read element offsets (K-iteration invariant)
  const int q = lane >> 4, rl = lane & 15;
  int aoff[4][2], boff[4][2];
#pragma unroll
  for (int t = 0; t < 4; ++t) {
#pragma unroll
    for (int ks = 0; ks < 2; ++ks) {
      int ra = wm * 64 + t * 16 + rl;
      int ca = ks * 4 + q;
      aoff[t][ks] = ra * 64 + ((ca ^ (ra & 7)) * 8);
      int rb = wn * 64 + t * 16 + rl;
      boff[t][ks] = rb * 64 + ((ca ^ (rb & 7)) * 8);
    }
  }

  f32x4_t acc[4][4];
#pragma unroll
  for (int i = 0; i < 4; ++i)
#pragma unroll
    for (int j = 0; j < 4; ++j) acc[i][j] = (f32x4_t){0.f, 0.f, 0.f, 0.f};

  for (int k0 = 0; k0 < K; k0 += 64) {
    __syncthreads();  // previous tile fully consumed
#pragma unroll
    for (int i = 0; i < 4; ++i) {
      GLOAD_LDS16(&A[(long long)(m0 + srow[i]) * lda + k0 + scol[i]],
                  &As[(w * 4 + i) * 512]);
    }
#pragma unroll
    for (int i = 0; i < 4; ++i) {
      GLOAD_LDS16(&B[(long long)(n0 + srow[i]) * ldb + k0 + scol[i]],
                  &Bs[(w * 4 + i) * 512]);
    }
    __syncthreads();  // drains vmcnt(0): tiles resident

#pragma unroll
    for (int ks = 0; ks < 2; ++ks) {
      bf16x8_t af[4], bg[4];
#pragma unroll
      for (int t = 0; t < 4; ++t) af[t] = *(const bf16x8_t*)&As[aoff[t][ks]];
#pragma unroll
      for (int t = 0; t < 4; ++t) bg[t] = *(const bf16x8_t*)&Bs[boff[t][ks]];
#pragma unroll
      for (int i = 0; i < 4; ++i)
#pragma unroll
        for (int j = 0; j < 4; ++j)
          acc[i][j] = __builtin_amdgcn_mfma_f32_16x16x32_bf16(af[i], bg[j],
                                                              acc[i][j], 0, 0, 0);
    }
  }

  // epilogue: C[row=(l>>4)*4+j][col=l&15] per fragment
  if (OUT_BF16) {
    unsigned short* C = (unsigned short*)Cv + (long long)z * sC;
#pragma unroll
    for (int t = 0; t < 4; ++t)
#pragma unroll
      for (int u = 0; u < 4; ++u)
#pragma unroll
        for (int j = 0; j < 4; ++j) {
          int row = m0 + wm * 64 + t * 16 + q * 4 + j;
          int col = n0 + wn * 64 + u * 16 + rl;
          C[(long long)row * ldc + col] = f2bf(acc[t][u][j] * alpha);
        }
  } else {
    float* C = (float*)Cv + (long long)z * sC;
#pragma unroll
    for (int t = 0; t < 4; ++t)
#pragma unroll
      for (int u = 0; u < 4; ++u)
#pragma unroll
        for (int j = 0; j < 4; ++j) {
          int row = m0 + wm * 64 + t * 16 + q * 4 + j;
          int col = n0 + wn * 64 + u * 16 + rl;
          C[(long long)row * ldc + col] = acc[t][u][j] * alpha;
        }
  }
}

// ---------------------------------------------------------------------------
// in-place row softmax on bf16 rows of 2048; fp32 internal math.
__global__ __launch_bounds__(256) void softmax_bf16(
    unsigned short* __restrict__ S) {
  unsigned short* p = S + (long long)blockIdx.x * 2048;
  const int tid = threadIdx.x;

  u16x8_t v = ((u16x8_t*)p)[tid];
  float f[8];
#pragma unroll
  for (int j = 0; j < 8; ++j) f[j] = bf2f(v[j]);

  float m = f[0];
#pragma unroll
  for (int j = 1; j < 8; ++j) m = fmaxf(m, f[j]);
#pragma unroll
  for (int off = 32; off > 0; off >>= 1) m = fmaxf(m, __shfl_xor(m, off));

  __shared__ float redm[4];
  __shared__ float reds[4];
  if ((tid & 63) == 0) redm[tid >> 6] = m;
  __syncthreads();
  m = fmaxf(fmaxf(redm[0], redm[1]), fmaxf(redm[2], redm[3]));

  float s = 0.f;
#pragma unroll
  for (int j = 0; j < 8; ++j) {
    f[j] = __expf(f[j] - m);
    s += f[j];
  }
#pragma unroll
  for (int off = 32; off > 0; off >>= 1) s += __shfl_xor(s, off);
  if ((tid & 63) == 0) reds[tid >> 6] = s;
  __syncthreads();
  s = (reds[0] + reds[1]) + (reds[2] + reds[3]);

  const float inv = 1.0f / s;
#pragma unroll
  for (int j = 0; j < 8; ++j) v[j] = f2bf(f[j] * inv);
  ((u16x8_t*)p)[tid] = v;
}

// ---------------------------------------------------------------------------
extern "C" void kernel_launch(void* const* d_in, const int* in_sizes, int n_in,
                              void* d_out, int out_size, void* d_ws,
                              size_t ws_size, hipStream_t stream) {
  const float* x = (const float*)d_in[0];
  const float* Wq = (const float*)d_in[1];
  const float* Wk = (const float*)d_in[2];
  const float* Wv = (const float*)d_in[3];
  float* out = (float*)d_out;

  // workspace layout (ushort elements)
  unsigned short* xb = (unsigned short*)d_ws;                  // 8192x1024
  unsigned short* Wqb = xb + 8388608;                          // 1024x1024
  unsigned short* Wkb = Wqb + 1048576;
  unsigned short* Wvb = Wkb + 1048576;
  unsigned short* Qb = Wvb + 1048576;                          // 8192x1024
  unsigned short* Kb = Qb + 8388608;                           // 8192x1024
  unsigned short* VTb = Kb + 8388608;                          // 1024x8192
  unsigned short* Scb = VTb + 8388608;                         // 4x2048x2048

  const dim3 blk(256);

  cast_f32_bf16<<<4096, blk, 0, stream>>>(x, xb, 1048576);
  cast_f32_bf16<<<512, blk, 0, stream>>>(Wq, Wqb, 131072);
  cast_f32_bf16<<<512, blk, 0, stream>>>(Wk, Wkb, 131072);
  cast_f32_bf16<<<512, blk, 0, stream>>>(Wv, Wvb, 131072);

  // Q = x.Wq^T [8192,1024]; K = x.Wk^T; V^T = Wv.x^T [1024,8192]
  gemm_nt<true><<<dim3(8, 64, 1), blk, 0, stream>>>(
      xb, Wqb, Qb, 8192, 1024, 1024, 1024, 1024, 1024, 0, 0, 0, 1.0f);
  gemm_nt<true><<<dim3(8, 64, 1), blk, 0, stream>>>(
      xb, Wkb, Kb, 8192, 1024, 1024, 1024, 1024, 1024, 0, 0, 0, 1.0f);
  gemm_nt<true><<<dim3(64, 8, 1), blk, 0, stream>>>(
      Wvb, xb, VTb, 1024, 8192, 1024, 1024, 1024, 8192, 0, 0, 0, 1.0f);

  // scores = (1/32) Qb.Kb^T  per batch -> bf16, in-place softmax
  gemm_nt<true><<<dim3(16, 16, 4), blk, 0, stream>>>(
      Qb, Kb, Scb, 2048, 2048, 1024, 1024, 1024, 2048, (long long)2048 * 1024,
      (long long)2048 * 1024, (long long)2048 * 2048, 0.03125f);

  softmax_bf16<<<8192, blk, 0, stream>>>(Scb);

  // out = P.(V^T)^T : A=P [2048,2048] lda=2048, B=VT rows ldb=8192 (z-offset
  // 2048 cols), C fp32 [2048,1024]
  gemm_nt<false><<<dim3(8, 16, 4), blk, 0, stream>>>(
      Scb, VTb, out, 2048, 1024, 2048, 2048, 8192, 1024,
      (long long)2048 * 2048, 2048, (long long)2048 * 1024, 1.0f);
}

// Round 4
// 194.551 us; speedup vs baseline: 11.2700x; 1.0176x over previous
//
#include <hip/hip_runtime.h>
#include <hip/hip_bf16.h>

// Self-attention, MODEL_DIM=1024, BATCH=4, SEQ=2048.
// bf16 MFMA pipeline: cast -> {Q,K} batched projection + V^T projection ->
// scores=Q.K^T (z-batched, alpha=1/32, bf16) -> in-place softmax ->
// out = P.(V^T)^T (NT GEMM, BN=64 tile, fp32 out).
// R4: batched QK dispatch (1024 WGs) + BN=64 PV tile (1024 WGs) for occupancy.

typedef short bf16x8_t __attribute__((ext_vector_type(8)));
typedef float f32x4_t __attribute__((ext_vector_type(4)));
typedef unsigned short u16x8_t __attribute__((ext_vector_type(8)));

static __device__ __forceinline__ unsigned short f2bf(float f) {
  __hip_bfloat16 h = __float2bfloat16(f);
  return *reinterpret_cast<unsigned short*>(&h);
}
static __device__ __forceinline__ float bf2f(unsigned short u) {
  return __uint_as_float(((unsigned int)u) << 16);
}

#define GLOAD_LDS16(gp, lp)                                            \
  __builtin_amdgcn_global_load_lds(                                    \
      (const __attribute__((address_space(1))) void*)(gp),             \
      (__attribute__((address_space(3))) void*)(lp), 16, 0, 0)

// ---------------------------------------------------------------------------
// cast fp32 -> bf16, 8 elements/thread
__global__ __launch_bounds__(256) void cast_f32_bf16(
    const float* __restrict__ in, unsigned short* __restrict__ out, int n8) {
  int i = blockIdx.x * 256 + threadIdx.x;
  if (i >= n8) return;
  float4 a = ((const float4*)in)[i * 2];
  float4 b = ((const float4*)in)[i * 2 + 1];
  u16x8_t o;
  o[0] = f2bf(a.x);
  o[1] = f2bf(a.y);
  o[2] = f2bf(a.z);
  o[3] = f2bf(a.w);
  o[4] = f2bf(b.x);
  o[5] = f2bf(b.y);
  o[6] = f2bf(b.z);
  o[7] = f2bf(b.w);
  ((u16x8_t*)out)[i] = o;
}

// ---------------------------------------------------------------------------
// NT bf16 GEMM: C[M,N] = alpha * A[M,K] * B[N,K]^T   (all row-major)
// Tile 128 x BN (BN = 128 or 64), BK=64, 256 threads = 4 waves (2x2),
// wave tile 64 x BN/2, v_mfma_f32_16x16x32_bf16.
// LDS tiles [rows][64] bf16, chunk-swizzled: phys_chunk = r*8 + (c8 ^ (r&7)).
// Staged via global_load_lds (linear LDS dest, pre-swizzled global source).
// Block ids XCD-swizzled (bijective; all grids have nwg % 8 == 0).
template <bool OUT_BF16, int BN>
__global__ __launch_bounds__(256) void gemm_nt(
    const unsigned short* __restrict__ A, const unsigned short* __restrict__ B,
    void* __restrict__ Cv, int M, int N, int K, int lda, int ldb, int ldc,
    long long sA, long long sB, long long sC, float alpha) {
  constexpr int NB = BN / 32;   // B-staging insts per wave; B frags per wave
  __shared__ unsigned short As[128 * 64];
  __shared__ unsigned short Bs[BN * 64];

  // ---- T1: bijective XCD swizzle ----
  const int gx = gridDim.x, gy = gridDim.y;
  const int nwg = gx * gy * gridDim.z;
  const int orig = (blockIdx.z * gy + blockIdx.y) * gx + blockIdx.x;
  const int swz = (orig & 7) * (nwg >> 3) + (orig >> 3);
  const int bx = swz % gx;
  const int tmp = swz / gx;
  const int by = tmp % gy;
  const int z = tmp / gy;

  const int tid = threadIdx.x;
  const int lane = tid & 63;
  const int w = tid >> 6;
  const int wm = w >> 1, wn = w & 1;
  const int m0 = by * 128;
  const int n0 = bx * BN;

  A += (long long)z * sA;
  B += (long long)z * sB;

  // staging: lane -> one 8-elem chunk per inst; phys = r*8 + (c8 ^ (r&7)).
  int sarow[4], sacol[4];
#pragma unroll
  for (int i = 0; i < 4; ++i) {
    int p = w * 256 + i * 64 + lane;
    int r = p >> 3;
    int c8 = (p & 7) ^ (r & 7);
    sarow[i] = r;
    sacol[i] = c8 * 8;
  }
  int sbrow[NB], sbcol[NB];
#pragma unroll
  for (int i = 0; i < NB; ++i) {
    int p = w * (BN * 2) + i * 64 + lane;
    int r = p >> 3;
    int c8 = (p & 7) ^ (r & 7);
    sbrow[i] = r;
    sbcol[i] = c8 * 8;
  }

  // ds_read element offsets (K-iteration invariant)
  const int q = lane >> 4, rl = lane & 15;
  int aoff[4][2], boff[NB][2];
#pragma unroll
  for (int t = 0; t < 4; ++t) {
#pragma unroll
    for (int ks = 0; ks < 2; ++ks) {
      int ra = wm * 64 + t * 16 + rl;
      int ca = ks * 4 + q;
      aoff[t][ks] = ra * 64 + ((ca ^ (ra & 7)) * 8);
    }
  }
#pragma unroll
  for (int u = 0; u < NB; ++u) {
#pragma unroll
    for (int ks = 0; ks < 2; ++ks) {
      int rb = wn * (BN / 2) + u * 16 + rl;
      int ca = ks * 4 + q;
      boff[u][ks] = rb * 64 + ((ca ^ (rb & 7)) * 8);
    }
  }

  f32x4_t acc[4][NB];
#pragma unroll
  for (int i = 0; i < 4; ++i)
#pragma unroll
    for (int j = 0; j < NB; ++j) acc[i][j] = (f32x4_t){0.f, 0.f, 0.f, 0.f};

  for (int k0 = 0; k0 < K; k0 += 64) {
    __syncthreads();  // previous tile fully consumed
#pragma unroll
    for (int i = 0; i < 4; ++i) {
      GLOAD_LDS16(&A[(long long)(m0 + sarow[i]) * lda + k0 + sacol[i]],
                  &As[(w * 4 + i) * 512]);
    }
#pragma unroll
    for (int i = 0; i < NB; ++i) {
      GLOAD_LDS16(&B[(long long)(n0 + sbrow[i]) * ldb + k0 + sbcol[i]],
                  &Bs[(w * NB + i) * 512]);
    }
    __syncthreads();  // drains vmcnt(0): tiles resident

#pragma unroll
    for (int ks = 0; ks < 2; ++ks) {
      bf16x8_t af[4], bg[NB];
#pragma unroll
      for (int t = 0; t < 4; ++t) af[t] = *(const bf16x8_t*)&As[aoff[t][ks]];
#pragma unroll
      for (int u = 0; u < NB; ++u) bg[u] = *(const bf16x8_t*)&Bs[boff[u][ks]];
#pragma unroll
      for (int i = 0; i < 4; ++i)
#pragma unroll
        for (int j = 0; j < NB; ++j)
          acc[i][j] = __builtin_amdgcn_mfma_f32_16x16x32_bf16(af[i], bg[j],
                                                              acc[i][j], 0, 0, 0);
    }
  }

  // epilogue: C[row=(l>>4)*4+j][col=l&15] per fragment
  if (OUT_BF16) {
    unsigned short* C = (unsigned short*)Cv + (long long)z * sC;
#pragma unroll
    for (int t = 0; t < 4; ++t)
#pragma unroll
      for (int u = 0; u < NB; ++u)
#pragma unroll
        for (int j = 0; j < 4; ++j) {
          int row = m0 + wm * 64 + t * 16 + q * 4 + j;
          int col = n0 + wn * (BN / 2) + u * 16 + rl;
          C[(long long)row * ldc + col] = f2bf(acc[t][u][j] * alpha);
        }
  } else {
    float* C = (float*)Cv + (long long)z * sC;
#pragma unroll
    for (int t = 0; t < 4; ++t)
#pragma unroll
      for (int u = 0; u < NB; ++u)
#pragma unroll
        for (int j = 0; j < 4; ++j) {
          int row = m0 + wm * 64 + t * 16 + q * 4 + j;
          int col = n0 + wn * (BN / 2) + u * 16 + rl;
          C[(long long)row * ldc + col] = acc[t][u][j] * alpha;
        }
  }
}

// ---------------------------------------------------------------------------
// in-place row softmax on bf16 rows of 2048; fp32 internal math.
__global__ __launch_bounds__(256) void softmax_bf16(
    unsigned short* __restrict__ S) {
  unsigned short* p = S + (long long)blockIdx.x * 2048;
  const int tid = threadIdx.x;

  u16x8_t v = ((u16x8_t*)p)[tid];
  float f[8];
#pragma unroll
  for (int j = 0; j < 8; ++j) f[j] = bf2f(v[j]);

  float m = f[0];
#pragma unroll
  for (int j = 1; j < 8; ++j) m = fmaxf(m, f[j]);
#pragma unroll
  for (int off = 32; off > 0; off >>= 1) m = fmaxf(m, __shfl_xor(m, off));

  __shared__ float redm[4];
  __shared__ float reds[4];
  if ((tid & 63) == 0) redm[tid >> 6] = m;
  __syncthreads();
  m = fmaxf(fmaxf(redm[0], redm[1]), fmaxf(redm[2], redm[3]));

  float s = 0.f;
#pragma unroll
  for (int j = 0; j < 8; ++j) {
    f[j] = __expf(f[j] - m);
    s += f[j];
  }
#pragma unroll
  for (int off = 32; off > 0; off >>= 1) s += __shfl_xor(s, off);
  if ((tid & 63) == 0) reds[tid >> 6] = s;
  __syncthreads();
  s = (reds[0] + reds[1]) + (reds[2] + reds[3]);

  const float inv = 1.0f / s;
#pragma unroll
  for (int j = 0; j < 8; ++j) v[j] = f2bf(f[j] * inv);
  ((u16x8_t*)p)[tid] = v;
}

// ---------------------------------------------------------------------------
extern "C" void kernel_launch(void* const* d_in, const int* in_sizes, int n_in,
                              void* d_out, int out_size, void* d_ws,
                              size_t ws_size, hipStream_t stream) {
  const float* x = (const float*)d_in[0];
  const float* Wq = (const float*)d_in[1];
  const float* Wk = (const float*)d_in[2];
  const float* Wv = (const float*)d_in[3];
  float* out = (float*)d_out;

  // workspace layout (ushort elements) -- Wqb/Wkb contiguous, Qb/Kb contiguous
  unsigned short* xb = (unsigned short*)d_ws;                  // 8192x1024
  unsigned short* Wqb = xb + 8388608;                          // 1024x1024
  unsigned short* Wkb = Wqb + 1048576;
  unsigned short* Wvb = Wkb + 1048576;
  unsigned short* Qb = Wvb + 1048576;                          // 8192x1024
  unsigned short* Kb = Qb + 8388608;                           // 8192x1024
  unsigned short* VTb = Kb + 8388608;                          // 1024x8192
  unsigned short* Scb = VTb + 8388608;                         // 4x2048x2048

  const dim3 blk(256);

  cast_f32_bf16<<<4096, blk, 0, stream>>>(x, xb, 1048576);
  cast_f32_bf16<<<512, blk, 0, stream>>>(Wq, Wqb, 131072);
  cast_f32_bf16<<<512, blk, 0, stream>>>(Wk, Wkb, 131072);
  cast_f32_bf16<<<512, blk, 0, stream>>>(Wv, Wvb, 131072);

  // {Q,K} = x.{Wq,Wk}^T batched over z (A shared, B/C strided) -> 1024 WGs
  gemm_nt<true, 128><<<dim3(8, 64, 2), blk, 0, stream>>>(
      xb, Wqb, Qb, 8192, 1024, 1024, 1024, 1024, 1024, 0, 1048576,
      8388608, 1.0f);
  // V^T = Wv.x^T [1024,8192]
  gemm_nt<true, 128><<<dim3(64, 8, 1), blk, 0, stream>>>(
      Wvb, xb, VTb, 1024, 8192, 1024, 1024, 1024, 8192, 0, 0, 0, 1.0f);

  // scores = (1/32) Qb.Kb^T  per batch -> bf16, in-place softmax
  gemm_nt<true, 128><<<dim3(16, 16, 4), blk, 0, stream>>>(
      Qb, Kb, Scb, 2048, 2048, 1024, 1024, 1024, 2048, (long long)2048 * 1024,
      (long long)2048 * 1024, (long long)2048 * 2048, 0.03125f);

  softmax_bf16<<<8192, blk, 0, stream>>>(Scb);

  // out = P.(V^T)^T : A=P [2048,2048] lda=2048, B=VT rows ldb=8192 (z-offset
  // 2048 cols), C fp32 [2048,1024]; BN=64 tile -> 1024 WGs
  gemm_nt<false, 64><<<dim3(16, 16, 4), blk, 0, stream>>>(
      Scb, VTb, out, 2048, 1024, 2048, 2048, 8192, 1024,
      (long long)2048 * 2048, 2048, (long long)2048 * 1024, 1.0f);
}

// Round 5
// 169.690 us; speedup vs baseline: 12.9211x; 1.1465x over previous
//
#include <hip/hip_runtime.h>
#include <hip/hip_bf16.h>

// Self-attention, MODEL_DIM=1024, BATCH=4, SEQ=2048.
// R5: 256^2-tile counted-vmcnt GEMM (T3+T4+T5) for merged-QK proj and scores;
// scores epilogue emits exp(s) bf16 + atomic f32 rowsums (softmax kernel
// eliminated); PV divides by rowsum in epilogue. VT/PV stay on 128^2 kernel.

typedef short bf16x8_t __attribute__((ext_vector_type(8)));
typedef float f32x4_t __attribute__((ext_vector_type(4)));
typedef unsigned short u16x8_t __attribute__((ext_vector_type(8)));

static __device__ __forceinline__ unsigned short f2bf(float f) {
  __hip_bfloat16 h = __float2bfloat16(f);
  return *reinterpret_cast<unsigned short*>(&h);
}

#define GLOAD_LDS16(gp, lp)                                            \
  __builtin_amdgcn_global_load_lds(                                    \
      (const __attribute__((address_space(1))) void*)(gp),             \
      (__attribute__((address_space(3))) void*)(lp), 16, 0, 0)

// ---------------------------------------------------------------------------
__global__ __launch_bounds__(256) void cast_f32_bf16(
    const float* __restrict__ in, unsigned short* __restrict__ out, int n8) {
  int i = blockIdx.x * 256 + threadIdx.x;
  if (i >= n8) return;
  float4 a = ((const float4*)in)[i * 2];
  float4 b = ((const float4*)in)[i * 2 + 1];
  u16x8_t o;
  o[0] = f2bf(a.x); o[1] = f2bf(a.y); o[2] = f2bf(a.z); o[3] = f2bf(a.w);
  o[4] = f2bf(b.x); o[5] = f2bf(b.y); o[6] = f2bf(b.z); o[7] = f2bf(b.w);
  ((u16x8_t*)out)[i] = o;
}

// Wq,Wk -> stacked Wqk [2048,1024]; Wv -> Wvb. One dispatch.
__global__ __launch_bounds__(256) void cast_w3(
    const float* __restrict__ Wq, const float* __restrict__ Wk,
    const float* __restrict__ Wv, unsigned short* __restrict__ Wqk,
    unsigned short* __restrict__ Wvb) {
  int i = blockIdx.x * 256 + threadIdx.x;  // chunk of 8 elems
  int seg = i >> 17;                        // 131072 chunks per matrix
  int local = i & 131071;
  const float* src = (seg == 0) ? Wq : ((seg == 1) ? Wk : Wv);
  unsigned short* dst =
      (seg == 0) ? Wqk : ((seg == 1) ? (Wqk + 1048576) : Wvb);
  float4 a = ((const float4*)src)[local * 2];
  float4 b = ((const float4*)src)[local * 2 + 1];
  u16x8_t o;
  o[0] = f2bf(a.x); o[1] = f2bf(a.y); o[2] = f2bf(a.z); o[3] = f2bf(a.w);
  o[4] = f2bf(b.x); o[5] = f2bf(b.y); o[6] = f2bf(b.z); o[7] = f2bf(b.w);
  ((u16x8_t*)dst)[local] = o;
}

__global__ __launch_bounds__(256) void zero_f32(float* __restrict__ p, int n) {
  int i = blockIdx.x * 256 + threadIdx.x;
  if (i < n) p[i] = 0.0f;
}

// ---------------------------------------------------------------------------
// 256x256-tile NT bf16 GEMM, BK=64, 512 threads = 8 waves (2M x 4N),
// per-wave 128x64 output (8x4 frags of v_mfma_f32_16x16x32_bf16).
// LDS: 2 buffers x (A 256x64 + B 256x64) bf16 = 128 KiB, chunk-XOR swizzled
// (phys_chunk = r*8 + (c8 ^ (r&7))), filled via global_load_lds w/
// pre-swizzled global source. Counted vmcnt(8) pipeline: buffer for tile t+2
// is staged right after tile t's compute; never drains to 0 in the loop.
// EPI 0: C=bf16(alpha*acc). EPI 1: C=bf16(exp(alpha*acc)) + atomic rowsum.
template <int EPI>
__global__ __launch_bounds__(512, 2) void gemm256_nt(
    const unsigned short* __restrict__ A, const unsigned short* __restrict__ B,
    unsigned short* __restrict__ C, float* __restrict__ rowsum, int K,
    int lda, int ldb, int ldc, long long sA, long long sB, long long sC,
    float alpha, int rsz) {
  __shared__ unsigned short lds[2][2][256 * 64];

  // T1: bijective XCD swizzle (nwg % 8 == 0 for all grids used)
  const int gx = gridDim.x, gy = gridDim.y;
  const int nwg = gx * gy * gridDim.z;
  const int orig = (blockIdx.z * gy + blockIdx.y) * gx + blockIdx.x;
  const int swz = (orig & 7) * (nwg >> 3) + (orig >> 3);
  const int bx = swz % gx;
  const int tmp = swz / gx;
  const int by = tmp % gy;
  const int z = tmp / gy;

  const int tid = threadIdx.x;
  const int lane = tid & 63;
  const int w = tid >> 6;           // 0..7
  const int wm = w >> 2, wn = w & 3;
  const int m0 = by * 256, n0 = bx * 256;

  A += (long long)z * sA;
  B += (long long)z * sB;

  // staging indices: inst i covers phys chunks [i*512 + w*64, +64)
  int sar[4], sac[4];
#pragma unroll
  for (int i = 0; i < 4; ++i) {
    int p = i * 512 + w * 64 + lane;
    int r = p >> 3;
    sar[i] = r;
    sac[i] = ((p & 7) ^ (r & 7)) * 8;
  }

  // ds_read element offsets (K-iteration invariant)
  const int q = lane >> 4, rl = lane & 15;
  int aoff[8][2], boff[4][2];
#pragma unroll
  for (int t = 0; t < 8; ++t)
#pragma unroll
    for (int ks = 0; ks < 2; ++ks) {
      int ra = wm * 128 + t * 16 + rl;
      int ca = ks * 4 + q;
      aoff[t][ks] = ra * 64 + ((ca ^ (ra & 7)) * 8);
    }
#pragma unroll
  for (int u = 0; u < 4; ++u)
#pragma unroll
    for (int ks = 0; ks < 2; ++ks) {
      int rb = wn * 64 + u * 16 + rl;
      int ca = ks * 4 + q;
      boff[u][ks] = rb * 64 + ((ca ^ (rb & 7)) * 8);
    }

  f32x4_t acc[8][4];
#pragma unroll
  for (int i = 0; i < 8; ++i)
#pragma unroll
    for (int j = 0; j < 4; ++j) acc[i][j] = (f32x4_t){0.f, 0.f, 0.f, 0.f};

#define STAGE256(bufi, k0)                                                   \
  {                                                                          \
    _Pragma("unroll") for (int i = 0; i < 4; ++i)                            \
        GLOAD_LDS16(&A[(long long)(m0 + sar[i]) * lda + (k0) + sac[i]],      \
                    &lds[bufi][0][(i * 512 + w * 64) * 8]);                  \
    _Pragma("unroll") for (int i = 0; i < 4; ++i)                            \
        GLOAD_LDS16(&B[(long long)(n0 + sar[i]) * ldb + (k0) + sac[i]],      \
                    &lds[bufi][1][(i * 512 + w * 64) * 8]);                  \
  }

  const int NT = K >> 6;
  STAGE256(0, 0);
  STAGE256(1, 64);

  for (int t = 0; t < NT; ++t) {
    const int cur = t & 1;
    // wait for buf[cur]'s 8 loads (8 newer in flight for buf[cur^1])
    if (t < NT - 1)
      asm volatile("s_waitcnt vmcnt(8)" ::: "memory");
    else
      asm volatile("s_waitcnt vmcnt(0)" ::: "memory");
    __builtin_amdgcn_s_barrier();
    __builtin_amdgcn_sched_barrier(0);
    const unsigned short* Al = &lds[cur][0][0];
    const unsigned short* Bl = &lds[cur][1][0];
#pragma unroll
    for (int ks = 0; ks < 2; ++ks) {
      bf16x8_t af[8], bg[4];
#pragma unroll
      for (int tt = 0; tt < 8; ++tt)
        af[tt] = *(const bf16x8_t*)&Al[aoff[tt][ks]];
#pragma unroll
      for (int u = 0; u < 4; ++u) bg[u] = *(const bf16x8_t*)&Bl[boff[u][ks]];
      __builtin_amdgcn_s_setprio(1);
#pragma unroll
      for (int i = 0; i < 8; ++i)
#pragma unroll
        for (int j = 0; j < 4; ++j)
          acc[i][j] = __builtin_amdgcn_mfma_f32_16x16x32_bf16(af[i], bg[j],
                                                              acc[i][j], 0, 0, 0);
      __builtin_amdgcn_s_setprio(0);
    }
    __builtin_amdgcn_sched_barrier(0);
    __builtin_amdgcn_s_barrier();       // all reads of buf[cur] done
    __builtin_amdgcn_sched_barrier(0);
    if (t + 2 < NT) STAGE256(cur, (t + 2) * 64);  // refill buf[cur] for t+2
  }

  // ---- epilogue ----
  if (EPI == 0) {
#pragma unroll
    for (int tt = 0; tt < 8; ++tt)
#pragma unroll
      for (int u = 0; u < 4; ++u)
#pragma unroll
        for (int j = 0; j < 4; ++j) {
          int row = m0 + wm * 128 + tt * 16 + q * 4 + j;
          int col = n0 + wn * 64 + u * 16 + rl;
          C[(long long)z * sC + (long long)row * ldc + col] =
              f2bf(acc[tt][u][j] * alpha);
        }
  } else {
#pragma unroll
    for (int tt = 0; tt < 8; ++tt)
#pragma unroll
      for (int j = 0; j < 4; ++j) {
        int row = m0 + wm * 128 + tt * 16 + q * 4 + j;
        float sum = 0.f;
#pragma unroll
        for (int u = 0; u < 4; ++u) {
          float e = __expf(acc[tt][u][j] * alpha);
          int col = n0 + wn * 64 + u * 16 + rl;
          C[(long long)z * sC + (long long)row * ldc + col] = f2bf(e);
          sum += e;
        }
#pragma unroll
        for (int mk = 1; mk <= 8; mk <<= 1) sum += __shfl_xor(sum, mk);
        if (rl == 0) atomicAdd(&rowsum[z * rsz + row], sum);
      }
  }
#undef STAGE256
}

// ---------------------------------------------------------------------------
// 128 x BN NT bf16 GEMM (R4 structure). EPI 0: bf16*alpha. 1: f32*alpha.
// 2: f32 / rowsum[row].
template <int EPI, int BN>
__global__ __launch_bounds__(256) void gemm_nt(
    const unsigned short* __restrict__ A, const unsigned short* __restrict__ B,
    void* __restrict__ Cv, const float* __restrict__ rowsum, int M, int N,
    int K, int lda, int ldb, int ldc, long long sA, long long sB,
    long long sC, float alpha, int rsz) {
  constexpr int NB = BN / 32;
  __shared__ unsigned short As[128 * 64];
  __shared__ unsigned short Bs[BN * 64];

  const int gx = gridDim.x, gy = gridDim.y;
  const int nwg = gx * gy * gridDim.z;
  const int orig = (blockIdx.z * gy + blockIdx.y) * gx + blockIdx.x;
  const int swz = (orig & 7) * (nwg >> 3) + (orig >> 3);
  const int bx = swz % gx;
  const int tmp = swz / gx;
  const int by = tmp % gy;
  const int z = tmp / gy;

  const int tid = threadIdx.x;
  const int lane = tid & 63;
  const int w = tid >> 6;
  const int wm = w >> 1, wn = w & 1;
  const int m0 = by * 128;
  const int n0 = bx * BN;

  A += (long long)z * sA;
  B += (long long)z * sB;

  int sarow[4], sacol[4];
#pragma unroll
  for (int i = 0; i < 4; ++i) {
    int p = w * 256 + i * 64 + lane;
    int r = p >> 3;
    sarow[i] = r;
    sacol[i] = ((p & 7) ^ (r & 7)) * 8;
  }
  int sbrow[NB], sbcol[NB];
#pragma unroll
  for (int i = 0; i < NB; ++i) {
    int p = w * (BN * 2) + i * 64 + lane;
    int r = p >> 3;
    sbrow[i] = r;
    sbcol[i] = ((p & 7) ^ (r & 7)) * 8;
  }

  const int q = lane >> 4, rl = lane & 15;
  int aoff[4][2], boff[NB][2];
#pragma unroll
  for (int t = 0; t < 4; ++t)
#pragma unroll
    for (int ks = 0; ks < 2; ++ks) {
      int ra = wm * 64 + t * 16 + rl;
      int ca = ks * 4 + q;
      aoff[t][ks] = ra * 64 + ((ca ^ (ra & 7)) * 8);
    }
#pragma unroll
  for (int u = 0; u < NB; ++u)
#pragma unroll
    for (int ks = 0; ks < 2; ++ks) {
      int rb = wn * (BN / 2) + u * 16 + rl;
      int ca = ks * 4 + q;
      boff[u][ks] = rb * 64 + ((ca ^ (rb & 7)) * 8);
    }

  f32x4_t acc[4][NB];
#pragma unroll
  for (int i = 0; i < 4; ++i)
#pragma unroll
    for (int j = 0; j < NB; ++j) acc[i][j] = (f32x4_t){0.f, 0.f, 0.f, 0.f};

  for (int k0 = 0; k0 < K; k0 += 64) {
    __syncthreads();
#pragma unroll
    for (int i = 0; i < 4; ++i) {
      GLOAD_LDS16(&A[(long long)(m0 + sarow[i]) * lda + k0 + sacol[i]],
                  &As[(w * 4 + i) * 512]);
    }
#pragma unroll
    for (int i = 0; i < NB; ++i) {
      GLOAD_LDS16(&B[(long long)(n0 + sbrow[i]) * ldb + k0 + sbcol[i]],
                  &Bs[(w * NB + i) * 512]);
    }
    __syncthreads();

#pragma unroll
    for (int ks = 0; ks < 2; ++ks) {
      bf16x8_t af[4], bg[NB];
#pragma unroll
      for (int t = 0; t < 4; ++t) af[t] = *(const bf16x8_t*)&As[aoff[t][ks]];
#pragma unroll
      for (int u = 0; u < NB; ++u) bg[u] = *(const bf16x8_t*)&Bs[boff[u][ks]];
#pragma unroll
      for (int i = 0; i < 4; ++i)
#pragma unroll
        for (int j = 0; j < NB; ++j)
          acc[i][j] = __builtin_amdgcn_mfma_f32_16x16x32_bf16(af[i], bg[j],
                                                              acc[i][j], 0, 0, 0);
    }
  }

#pragma unroll
  for (int t = 0; t < 4; ++t)
#pragma unroll
    for (int u = 0; u < NB; ++u)
#pragma unroll
      for (int j = 0; j < 4; ++j) {
        int row = m0 + wm * 64 + t * 16 + q * 4 + j;
        int col = n0 + wn * (BN / 2) + u * 16 + rl;
        if (EPI == 0) {
          ((unsigned short*)Cv)[(long long)z * sC + (long long)row * ldc +
                                col] = f2bf(acc[t][u][j] * alpha);
        } else if (EPI == 1) {
          ((float*)Cv)[(long long)z * sC + (long long)row * ldc + col] =
              acc[t][u][j] * alpha;
        } else {
          float inv = 1.0f / rowsum[z * rsz + row];
          ((float*)Cv)[(long long)z * sC + (long long)row * ldc + col] =
              acc[t][u][j] * inv;
        }
      }
}

// ---------------------------------------------------------------------------
extern "C" void kernel_launch(void* const* d_in, const int* in_sizes, int n_in,
                              void* d_out, int out_size, void* d_ws,
                              size_t ws_size, hipStream_t stream) {
  const float* x = (const float*)d_in[0];
  const float* Wq = (const float*)d_in[1];
  const float* Wk = (const float*)d_in[2];
  const float* Wv = (const float*)d_in[3];
  float* out = (float*)d_out;

  // workspace (ushort elems)
  unsigned short* xb = (unsigned short*)d_ws;      // 8192x1024
  unsigned short* Wqk = xb + 8388608;              // 2048x1024 (Wq;Wk)
  unsigned short* Wvb = Wqk + 2097152;             // 1024x1024
  unsigned short* Cqk = Wvb + 1048576;             // 8192x2048 (Q|K)
  unsigned short* VTb = Cqk + 16777216;            // 1024x8192
  unsigned short* Scb = VTb + 8388608;             // 4x2048x2048
  float* rowsumf = (float*)(Scb + 16777216);       // 8192 f32

  const dim3 blk(256);
  const dim3 blk512(512);

  cast_f32_bf16<<<4096, blk, 0, stream>>>(x, xb, 1048576);
  cast_w3<<<1536, blk, 0, stream>>>(Wq, Wk, Wv, Wqk, Wvb);
  zero_f32<<<32, blk, 0, stream>>>(rowsumf, 8192);

  // [Q|K] = x . Wqk^T : M=8192, N=2048, K=1024 -> 256 WGs
  gemm256_nt<0><<<dim3(8, 32, 1), blk512, 0, stream>>>(
      xb, Wqk, Cqk, nullptr, 1024, 1024, 1024, 2048, 0, 0, 0, 1.0f, 0);

  // V^T = Wv . x^T [1024,8192] (128^2 kernel, 512 WGs)
  gemm_nt<0, 128><<<dim3(64, 8, 1), blk, 0, stream>>>(
      Wvb, xb, VTb, nullptr, 1024, 8192, 1024, 1024, 1024, 8192, 0, 0, 0,
      1.0f, 0);

  // E = exp(Q.K^T / 32) per batch -> bf16 + atomic rowsums; 256 WGs
  gemm256_nt<1><<<dim3(8, 8, 4), blk512, 0, stream>>>(
      Cqk, Cqk + 1024, Scb, rowsumf, 1024, 2048, 2048, 2048,
      (long long)2048 * 2048, (long long)2048 * 2048, (long long)2048 * 2048,
      0.03125f, 2048);

  // out = (E . V) / rowsum : 128x64 tiles, 1024 WGs
  gemm_nt<2, 64><<<dim3(16, 16, 4), blk, 0, stream>>>(
      Scb, VTb, out, rowsumf, 2048, 1024, 2048, 2048, 8192, 1024,
      (long long)2048 * 2048, 2048, (long long)2048 * 1024, 1.0f, 2048);
}

// Round 6
// 164.029 us; speedup vs baseline: 13.3670x; 1.0345x over previous
//
#include <hip/hip_runtime.h>
#include <hip/hip_bf16.h>

// Self-attention, MODEL_DIM=1024, BATCH=4, SEQ=2048.
// R6: true 8-phase counted-vmcnt 256-row GEMM (T2+T3+T4+T5) for QK-proj,
// scores (exp epilogue + atomic rowsum), and PV (BN=128, /rowsum, f32 out).
// VT stays on the verified 128^2 kernel.

typedef short bf16x8_t __attribute__((ext_vector_type(8)));
typedef float f32x4_t __attribute__((ext_vector_type(4)));
typedef unsigned short u16x8_t __attribute__((ext_vector_type(8)));

static __device__ __forceinline__ unsigned short f2bf(float f) {
  __hip_bfloat16 h = __float2bfloat16(f);
  return *reinterpret_cast<unsigned short*>(&h);
}

#define GLOAD_LDS16(gp, lp)                                            \
  __builtin_amdgcn_global_load_lds(                                    \
      (const __attribute__((address_space(1))) void*)(gp),             \
      (__attribute__((address_space(3))) void*)(lp), 16, 0, 0)

// ---------------------------------------------------------------------------
__global__ __launch_bounds__(256) void cast_f32_bf16(
    const float* __restrict__ in, unsigned short* __restrict__ out, int n8) {
  int i = blockIdx.x * 256 + threadIdx.x;
  if (i >= n8) return;
  float4 a = ((const float4*)in)[i * 2];
  float4 b = ((const float4*)in)[i * 2 + 1];
  u16x8_t o;
  o[0] = f2bf(a.x); o[1] = f2bf(a.y); o[2] = f2bf(a.z); o[3] = f2bf(a.w);
  o[4] = f2bf(b.x); o[5] = f2bf(b.y); o[6] = f2bf(b.z); o[7] = f2bf(b.w);
  ((u16x8_t*)out)[i] = o;
}

__global__ __launch_bounds__(256) void cast_w3(
    const float* __restrict__ Wq, const float* __restrict__ Wk,
    const float* __restrict__ Wv, unsigned short* __restrict__ Wqk,
    unsigned short* __restrict__ Wvb) {
  int i = blockIdx.x * 256 + threadIdx.x;
  int seg = i >> 17;
  int local = i & 131071;
  const float* src = (seg == 0) ? Wq : ((seg == 1) ? Wk : Wv);
  unsigned short* dst =
      (seg == 0) ? Wqk : ((seg == 1) ? (Wqk + 1048576) : Wvb);
  float4 a = ((const float4*)src)[local * 2];
  float4 b = ((const float4*)src)[local * 2 + 1];
  u16x8_t o;
  o[0] = f2bf(a.x); o[1] = f2bf(a.y); o[2] = f2bf(a.z); o[3] = f2bf(a.w);
  o[4] = f2bf(b.x); o[5] = f2bf(b.y); o[6] = f2bf(b.z); o[7] = f2bf(b.w);
  ((u16x8_t*)dst)[local] = o;
}

__global__ __launch_bounds__(256) void zero_f32(float* __restrict__ p, int n) {
  int i = blockIdx.x * 256 + threadIdx.x;
  if (i < n) p[i] = 0.0f;
}

// ---------------------------------------------------------------------------
// 256 x BN NT bf16 GEMM, BK=64, 512 threads = 8 waves (2M x 4N), 8-phase
// counted-vmcnt schedule. Per K-tile: 4 quadrant phases, each
// {ds_read subtile, issue 1 half-tile stage, barrier, lgkmcnt(0), MFMA
// cluster (setprio), barrier}. vmcnt counted once per tile at ph3 (never 0
// mid-loop). LDS chunk-XOR swizzled, staged via global_load_lds with
// pre-swizzled global source. Bijective XCD block swizzle.
// Stage schedule (tile t): ph0 -> A_m1(t+1), ph1 -> B_n0(t+1),
//                          ph2 -> A_m0(t+2), ph3 -> B_n1(t+2).
// Half-tiles are the exact row stripes phase (mh,nh) consumes:
//   A_mh = rows [mh*64,+64) u [128+mh*64,+64)
//   B_nh = U_wn [wn*BNW + nh*BNW/2, +BNW/2)
// EPI 0: bf16(alpha*acc). 1: bf16(exp(alpha*acc)) + atomic rowsum.
// 2: f32 acc/rowsum[row].
template <int EPI, int BN>
__global__ __launch_bounds__(512, 2) void gemm256p(
    const unsigned short* __restrict__ A, const unsigned short* __restrict__ B,
    void* __restrict__ Cv, float* __restrict__ rowsum, int K, int lda,
    int ldb, int ldc, long long sA, long long sB, long long sC, float alpha,
    int rsz) {
  constexpr int NBG = BN / 64;  // bg frags per wave (4 / 2)
  constexpr int NH = NBG / 2;   // bg frags per phase (2 / 1)
  constexpr int BL = BN / 128;  // B stage insts per wave (2 / 1)
  constexpr int BNW = BN / 4;   // wave n-extent (64 / 32)
  constexpr int ASZ = 256 * 64;
  constexpr int BSZ = BN * 64;

  __shared__ unsigned short lds[2][ASZ + BSZ];

  // T1: bijective XCD swizzle (nwg % 8 == 0 for all grids used)
  const int gx = gridDim.x, gy = gridDim.y;
  const int nwg = gx * gy * gridDim.z;
  const int orig = (blockIdx.z * gy + blockIdx.y) * gx + blockIdx.x;
  const int swz = (orig & 7) * (nwg >> 3) + (orig >> 3);
  const int bx = swz % gx;
  const int tmp = swz / gx;
  const int by = tmp % gy;
  const int z = tmp / gy;

  const int tid = threadIdx.x;
  const int lane = tid & 63;
  const int w = tid >> 6;
  const int wm = w >> 2, wn = w & 3;
  const int m0 = by * 256, n0 = bx * BN;

  A += (long long)z * sA;
  B += (long long)z * sB;

  // ---- staging index precompute (chunk l holds k-chunk (l&7)^(row&7)) ----
  int sta_row[2][2], sta_col[2][2], sta_lds[2][2];
#pragma unroll
  for (int mh = 0; mh < 2; ++mh)
#pragma unroll
    for (int i = 0; i < 2; ++i) {
      int j = w * 2 + i;  // 0..15
      int l0 = (j >> 3) * 1024 + mh * 512 + (j & 7) * 64;
      int lf = l0 + lane;
      int R = lf >> 3;
      sta_row[mh][i] = R;
      sta_col[mh][i] = ((lf & 7) ^ (R & 7)) * 8;
      sta_lds[mh][i] = l0 * 8;
    }
  int stb_row[2][BL], stb_col[2][BL], stb_lds[2][BL];
#pragma unroll
  for (int nh = 0; nh < 2; ++nh)
#pragma unroll
    for (int i = 0; i < BL; ++i) {
      int l0;
      if (BL == 2) {
        int j = w * 2 + i;  // 0..15
        l0 = (j >> 2) * 512 + nh * 256 + (j & 3) * 64;
      } else {
        int j = w;  // 0..7
        l0 = (j >> 1) * 256 + nh * 128 + (j & 1) * 64;
      }
      int lf = l0 + lane;
      int R = lf >> 3;
      stb_row[nh][i] = R;
      stb_col[nh][i] = ((lf & 7) ^ (R & 7)) * 8;
      stb_lds[nh][i] = ASZ + l0 * 8;
    }

  // ---- ds_read element offsets (K-invariant) ----
  const int q = lane >> 4, rl = lane & 15;
  int aoff[8][2], boff[NBG][2];
#pragma unroll
  for (int tt = 0; tt < 8; ++tt)
#pragma unroll
    for (int ks = 0; ks < 2; ++ks) {
      int ra = wm * 128 + tt * 16 + rl;
      aoff[tt][ks] = ra * 64 + (((ks * 4 + q) ^ (ra & 7)) * 8);
    }
#pragma unroll
  for (int u = 0; u < NBG; ++u)
#pragma unroll
    for (int ks = 0; ks < 2; ++ks) {
      int rb = wn * BNW + u * 16 + rl;
      boff[u][ks] = ASZ + rb * 64 + (((ks * 4 + q) ^ (rb & 7)) * 8);
    }

  f32x4_t acc[8][NBG];
#pragma unroll
  for (int i = 0; i < 8; ++i)
#pragma unroll
    for (int j = 0; j < NBG; ++j) acc[i][j] = (f32x4_t){0.f, 0.f, 0.f, 0.f};

#define SA(BUFI, MH, K0)                                                    \
  {                                                                         \
    _Pragma("unroll") for (int i_ = 0; i_ < 2; ++i_)                        \
        GLOAD_LDS16(&A[(long long)(m0 + sta_row[MH][i_]) * lda + (K0) +     \
                       sta_col[MH][i_]],                                    \
                    &lds[BUFI][sta_lds[MH][i_]]);                           \
  }
#define SB(BUFI, NH_, K0)                                                   \
  {                                                                         \
    _Pragma("unroll") for (int i_ = 0; i_ < BL; ++i_)                       \
        GLOAD_LDS16(&B[(long long)(n0 + stb_row[NH_][i_]) * ldb + (K0) +    \
                       stb_col[NH_][i_]],                                   \
                    &lds[BUFI][stb_lds[NH_][i_]]);                          \
  }
#define LDAF(MH)                                                            \
  _Pragma("unroll") for (int i_ = 0; i_ < 4; ++i_)                          \
  _Pragma("unroll") for (int ks_ = 0; ks_ < 2; ++ks_)                       \
      af[i_][ks_] = *(const bf16x8_t*)&L[aoff[(MH)*4 + i_][ks_]];
#define LDBG(NH_)                                                           \
  _Pragma("unroll") for (int j_ = 0; j_ < NH; ++j_)                         \
  _Pragma("unroll") for (int ks_ = 0; ks_ < 2; ++ks_)                       \
      bg[j_][ks_] = *(const bf16x8_t*)&L[boff[(NH_)*NH + j_][ks_]];
#define PH_MFMA(MH, NH_)                                                    \
  __builtin_amdgcn_s_barrier();                                             \
  asm volatile("s_waitcnt lgkmcnt(0)" ::: "memory");                        \
  __builtin_amdgcn_sched_barrier(0);                                        \
  __builtin_amdgcn_s_setprio(1);                                            \
  _Pragma("unroll") for (int ks_ = 0; ks_ < 2; ++ks_)                       \
  _Pragma("unroll") for (int i_ = 0; i_ < 4; ++i_)                          \
  _Pragma("unroll") for (int j_ = 0; j_ < NH; ++j_)                         \
      acc[(MH)*4 + i_][(NH_)*NH + j_] =                                     \
          __builtin_amdgcn_mfma_f32_16x16x32_bf16(                          \
              af[i_][ks_], bg[j_][ks_], acc[(MH)*4 + i_][(NH_)*NH + j_],    \
              0, 0, 0);                                                     \
  __builtin_amdgcn_s_setprio(0);                                            \
  __builtin_amdgcn_sched_barrier(0);                                        \
  __builtin_amdgcn_s_barrier();                                             \
  __builtin_amdgcn_sched_barrier(0);

  const int NT = K >> 6;

  // prologue: tile0 fully + tile1's A_m0, B_n1 (ph2/ph3-of-(t-1) equivalents)
  SA(0, 0, 0); SA(0, 1, 0); SB(0, 0, 0); SB(0, 1, 0);
  SA(1, 0, 64); SB(1, 1, 64);
  if (BL == 2)
    asm volatile("s_waitcnt vmcnt(4)" ::: "memory");
  else
    asm volatile("s_waitcnt vmcnt(3)" ::: "memory");
  __builtin_amdgcn_s_barrier();
  __builtin_amdgcn_sched_barrier(0);

  bf16x8_t af[4][2], bg[NH][2];

  for (int t = 0; t < NT; ++t) {
    const int bu = t & 1, nx = bu ^ 1;
    const unsigned short* L = lds[bu];
    const bool p1 = (t + 1 < NT), p2 = (t + 2 < NT);
    // ph0 (m0,n0): stage A_m1(t+1)
    LDAF(0);
    LDBG(0);
    if (p1) SA(nx, 1, (t + 1) * 64);
    PH_MFMA(0, 0);
    // ph1 (m0,n1): stage B_n0(t+1)
    LDBG(1);
    if (p1) SB(nx, 0, (t + 1) * 64);
    PH_MFMA(0, 1);
    // ph2 (m1,n1): stage A_m0(t+2)
    LDAF(1);
    if (p2) SA(bu, 0, (t + 2) * 64);
    PH_MFMA(1, 1);
    // ph3 (m1,n0): stage B_n1(t+2); counted vmcnt guards tile t+1's data
    LDBG(0);
    if (p2) {
      SB(bu, 1, (t + 2) * 64);
      if (BL == 2)
        asm volatile("s_waitcnt vmcnt(4)" ::: "memory");
      else
        asm volatile("s_waitcnt vmcnt(3)" ::: "memory");
    } else {
      asm volatile("s_waitcnt vmcnt(0)" ::: "memory");
    }
    PH_MFMA(1, 0);
  }

  // ---- epilogue ----
  if (EPI == 0) {
    unsigned short* C = (unsigned short*)Cv + (long long)z * sC;
#pragma unroll
    for (int tt = 0; tt < 8; ++tt)
#pragma unroll
      for (int u = 0; u < NBG; ++u)
#pragma unroll
        for (int j = 0; j < 4; ++j) {
          int row = m0 + wm * 128 + tt * 16 + q * 4 + j;
          int col = n0 + wn * BNW + u * 16 + rl;
          C[(long long)row * ldc + col] = f2bf(acc[tt][u][j] * alpha);
        }
  } else if (EPI == 1) {
    unsigned short* C = (unsigned short*)Cv + (long long)z * sC;
#pragma unroll
    for (int tt = 0; tt < 8; ++tt)
#pragma unroll
      for (int j = 0; j < 4; ++j) {
        int row = m0 + wm * 128 + tt * 16 + q * 4 + j;
        float sum = 0.f;
#pragma unroll
        for (int u = 0; u < NBG; ++u) {
          float e = __expf(acc[tt][u][j] * alpha);
          int col = n0 + wn * BNW + u * 16 + rl;
          C[(long long)row * ldc + col] = f2bf(e);
          sum += e;
        }
#pragma unroll
        for (int mk = 1; mk <= 8; mk <<= 1) sum += __shfl_xor(sum, mk);
        if (rl == 0) atomicAdd(&rowsum[z * rsz + row], sum);
      }
  } else {
    float* C = (float*)Cv + (long long)z * sC;
#pragma unroll
    for (int tt = 0; tt < 8; ++tt)
#pragma unroll
      for (int j = 0; j < 4; ++j) {
        int row = m0 + wm * 128 + tt * 16 + q * 4 + j;
        float inv = 1.0f / rowsum[z * rsz + row];
#pragma unroll
        for (int u = 0; u < NBG; ++u) {
          int col = n0 + wn * BNW + u * 16 + rl;
          C[(long long)row * ldc + col] = acc[tt][u][j] * inv;
        }
      }
  }
#undef SA
#undef SB
#undef LDAF
#undef LDBG
#undef PH_MFMA
}

// ---------------------------------------------------------------------------
// 128 x 128 NT bf16 GEMM (verified R2-R5 structure) -- used for V^T.
__global__ __launch_bounds__(256) void gemm_nt128(
    const unsigned short* __restrict__ A, const unsigned short* __restrict__ B,
    unsigned short* __restrict__ C, int K, int lda, int ldb, int ldc) {
  __shared__ unsigned short As[128 * 64];
  __shared__ unsigned short Bs[128 * 64];

  const int gx = gridDim.x, gy = gridDim.y;
  const int nwg = gx * gy;
  const int orig = blockIdx.y * gx + blockIdx.x;
  const int swz = (orig & 7) * (nwg >> 3) + (orig >> 3);
  const int bx = swz % gx;
  const int by = swz / gx;

  const int tid = threadIdx.x;
  const int lane = tid & 63;
  const int w = tid >> 6;
  const int wm = w >> 1, wn = w & 1;
  const int m0 = by * 128;
  const int n0 = bx * 128;

  int srow[4], scol[4];
#pragma unroll
  for (int i = 0; i < 4; ++i) {
    int p = w * 256 + i * 64 + lane;
    int r = p >> 3;
    srow[i] = r;
    scol[i] = ((p & 7) ^ (r & 7)) * 8;
  }

  const int q = lane >> 4, rl = lane & 15;
  int aoff[4][2], boff[4][2];
#pragma unroll
  for (int t = 0; t < 4; ++t)
#pragma unroll
    for (int ks = 0; ks < 2; ++ks) {
      int ra = wm * 64 + t * 16 + rl;
      int ca = ks * 4 + q;
      aoff[t][ks] = ra * 64 + ((ca ^ (ra & 7)) * 8);
      int rb = wn * 64 + t * 16 + rl;
      boff[t][ks] = rb * 64 + ((ca ^ (rb & 7)) * 8);
    }

  f32x4_t acc[4][4];
#pragma unroll
  for (int i = 0; i < 4; ++i)
#pragma unroll
    for (int j = 0; j < 4; ++j) acc[i][j] = (f32x4_t){0.f, 0.f, 0.f, 0.f};

  for (int k0 = 0; k0 < K; k0 += 64) {
    __syncthreads();
#pragma unroll
    for (int i = 0; i < 4; ++i) {
      GLOAD_LDS16(&A[(long long)(m0 + srow[i]) * lda + k0 + scol[i]],
                  &As[(w * 4 + i) * 512]);
      GLOAD_LDS16(&B[(long long)(n0 + srow[i]) * ldb + k0 + scol[i]],
                  &Bs[(w * 4 + i) * 512]);
    }
    __syncthreads();

#pragma unroll
    for (int ks = 0; ks < 2; ++ks) {
      bf16x8_t af[4], bgv[4];
#pragma unroll
      for (int t = 0; t < 4; ++t) af[t] = *(const bf16x8_t*)&As[aoff[t][ks]];
#pragma unroll
      for (int u = 0; u < 4; ++u) bgv[u] = *(const bf16x8_t*)&Bs[boff[u][ks]];
#pragma unroll
      for (int i = 0; i < 4; ++i)
#pragma unroll
        for (int j = 0; j < 4; ++j)
          acc[i][j] = __builtin_amdgcn_mfma_f32_16x16x32_bf16(
              af[i], bgv[j], acc[i][j], 0, 0, 0);
    }
  }

#pragma unroll
  for (int t = 0; t < 4; ++t)
#pragma unroll
    for (int u = 0; u < 4; ++u)
#pragma unroll
      for (int j = 0; j < 4; ++j) {
        int row = m0 + wm * 64 + t * 16 + q * 4 + j;
        int col = n0 + wn * 64 + u * 16 + rl;
        C[(long long)row * ldc + col] = f2bf(acc[t][u][j]);
      }
}

// ---------------------------------------------------------------------------
extern "C" void kernel_launch(void* const* d_in, const int* in_sizes, int n_in,
                              void* d_out, int out_size, void* d_ws,
                              size_t ws_size, hipStream_t stream) {
  const float* x = (const float*)d_in[0];
  const float* Wq = (const float*)d_in[1];
  const float* Wk = (const float*)d_in[2];
  const float* Wv = (const float*)d_in[3];
  float* out = (float*)d_out;

  // workspace (ushort elems)
  unsigned short* xb = (unsigned short*)d_ws;   // 8192x1024
  unsigned short* Wqk = xb + 8388608;           // 2048x1024 (Wq;Wk)
  unsigned short* Wvb = Wqk + 2097152;          // 1024x1024
  unsigned short* Cqk = Wvb + 1048576;          // 8192x2048 (Q|K)
  unsigned short* VTb = Cqk + 16777216;         // 1024x8192
  unsigned short* Scb = VTb + 8388608;          // 4x2048x2048 (exp scores)
  float* rowsumf = (float*)(Scb + 16777216);    // 8192 f32

  const dim3 blk(256);
  const dim3 blk512(512);

  cast_f32_bf16<<<4096, blk, 0, stream>>>(x, xb, 1048576);
  cast_w3<<<1536, blk, 0, stream>>>(Wq, Wk, Wv, Wqk, Wvb);
  zero_f32<<<32, blk, 0, stream>>>(rowsumf, 8192);

  // [Q|K] = x . Wqk^T : M=8192, N=2048, K=1024 -> 256 WGs
  gemm256p<0, 256><<<dim3(8, 32, 1), blk512, 0, stream>>>(
      xb, Wqk, Cqk, nullptr, 1024, 1024, 1024, 2048, 0, 0, 0, 1.0f, 0);

  // V^T = Wv . x^T [1024,8192]
  gemm_nt128<<<dim3(64, 8), blk, 0, stream>>>(Wvb, xb, VTb, 1024, 1024, 1024,
                                              8192);

  // E = exp(Q.K^T / 32) per batch -> bf16 + atomic rowsums; 256 WGs
  gemm256p<1, 256><<<dim3(8, 8, 4), blk512, 0, stream>>>(
      Cqk, Cqk + 1024, Scb, rowsumf, 1024, 2048, 2048, 2048,
      (long long)2048 * 2048, (long long)2048 * 2048, (long long)2048 * 2048,
      0.03125f, 2048);

  // out = (E . V) / rowsum : BN=128 -> grid (8,8,4) = 256 WGs
  gemm256p<2, 128><<<dim3(8, 8, 4), blk512, 0, stream>>>(
      Scb, VTb, out, rowsumf, 2048, 2048, 8192, 1024,
      (long long)2048 * 2048, 2048, (long long)2048 * 1024, 1.0f, 2048);
}